// Round 14
// baseline (30603.857 us; speedup 1.0000x reference)
//
#include <hip/hip_runtime.h>

// DARTS RNN cell, T=1024, B=64, NHID=NINP=256.
// Round 14: ONE-XCD TEAM. grid=256 (1 wg/CU, 32/XCD guaranteed); claim-based
// election picks the first XCD to assemble 16 wgs; the other 240 wgs exit.
// All cross-wg exchange (state frags + flags) is sc0-only: producer stores
// write through L1 into the XCD-SHARED L2; consumer sc0 loads bypass L1 and
// read that same L2 -> RT ~0.1us instead of MALL's ~0.45us.
// Hang-proofing: flags are published BOTH to an L2 copy (sc0) and a MALL
// copy (sc0 sc1, the r13-proven protocol). The wave-0 poll spins on the L2
// copy and falls back to checking the MALL copy after 16 iterations -> if
// sc0-L2 visibility is broken we degrade to ~r13 speed, never hang.
// (r2's one-XCD hang was re-diagnosed as a poll INDEX BUG, not coherence:
// it spun on flags[>63] which were never written.)
// Everything else = r13: wg-joint flags, single-poller, swapped MFMAs,
// dwordx2 exchange writes, s6/s7/s8 in slot-C window, Ws in LDS, W0 in VGPR.

#define TT 1024
#define NWG 16

typedef __attribute__((ext_vector_type(8))) short bf16x8;
typedef __attribute__((ext_vector_type(4))) float f32x4;
typedef __attribute__((ext_vector_type(2))) unsigned int u32x2;

__device__ __forceinline__ unsigned short f2bf(float f) {
  unsigned u = __builtin_bit_cast(unsigned, f);
  u += 0x7FFFu + ((u >> 16) & 1u);   // round-to-nearest-even
  return (unsigned short)(u >> 16);
}
__device__ __forceinline__ float sigm(float c) { return 1.0f / (1.0f + __expf(-c)); }
__device__ __forceinline__ float tanh_f(float h) {
  float e = __expf(2.0f * h);        // inf-safe
  return 1.0f - 2.0f / (e + 1.0f);
}

// L2-coherent (same-XCD) 16B load; pair with ASM_WAIT8 before use.
__device__ __forceinline__ void lda_sc(bf16x8& r, const void* p) {
  asm volatile("global_load_dwordx4 %0, %1, off sc0" : "=v"(r) : "v"(p));
}
#define ASM_WAIT8(A) asm volatile("s_waitcnt vmcnt(0)" \
  : "+v"((A)[0]), "+v"((A)[1]), "+v"((A)[2]), "+v"((A)[3]), \
    "+v"((A)[4]), "+v"((A)[5]), "+v"((A)[6]), "+v"((A)[7]) :: "memory")

// flags dwords: [0..15] MALL flag copies; [16..31] L2 flag copies;
// [64 + xcc*16] per-XCD arrival counters; [320] team claim (0=unclaimed).
__global__ void darts_init(const float* __restrict__ hid,
                           unsigned short* __restrict__ sf,
                           unsigned* __restrict__ flags) {
  int tid = blockIdx.x * 256 + threadIdx.x;  // 2048 threads
  if (tid < 512) flags[tid] = 0;
  int lane = tid & 63, mt = (tid >> 6) & 3, kc = tid >> 8;
  const float* ph = hid + (mt * 16 + (lane & 15)) * 256 + kc * 32 + (lane >> 4) * 8;
  bf16x8 v;
#pragma unroll
  for (int e = 0; e < 8; ++e) v[e] = (short)f2bf(ph[e]);
  *(bf16x8*)(sf + 6 * 16384 + tid * 8) = v;  // tid == ((kc*4+mt)*64+lane)
  // (kernel-end L2 writeback makes this visible to the main kernel's XCD)
}

__global__ void __launch_bounds__(256, 1) darts_main(
    const float* __restrict__ x, const float* __restrict__ hid,
    const float* __restrict__ W0g, const float* __restrict__ Wsg,
    float* __restrict__ out,
    unsigned short* __restrict__ sf, unsigned* __restrict__ flags) {
  const int tid = threadIdx.x;
  // ---- elect a 16-wg team on ONE XCD (each XCD gets 32 wgs -> some XCD
  // always assembles 16 -> claim always set -> no deadlock) ----
  unsigned xcc = __builtin_amdgcn_s_getreg(6164) & 0xFu;  // HW_REG_XCC_ID[3:0]
  __shared__ unsigned s_slot;
  if (tid == 0) {
    unsigned res = 0xFFFFFFFFu;
    unsigned slot = __hip_atomic_fetch_add(&flags[64 + xcc * 16], 1u,
                                           __ATOMIC_RELAXED, __HIP_MEMORY_SCOPE_AGENT);
    if (slot < NWG) {
      if (slot == NWG - 1) {  // 16th member of this XCD: claim the job
        unsigned exp = 0u;
        __hip_atomic_compare_exchange_strong(&flags[320], &exp, xcc + 1u,
            __ATOMIC_RELAXED, __ATOMIC_RELAXED, __HIP_MEMORY_SCOPE_AGENT);
      }
      unsigned c;
      do {
        c = __hip_atomic_load(&flags[320], __ATOMIC_RELAXED, __HIP_MEMORY_SCOPE_AGENT);
      } while (c == 0u);
      if (c == xcc + 1u) res = slot;  // our XCD won
    }
    s_slot = res;
  }
  __syncthreads();
  if (s_slot >= NWG) return;
  const int wg = (int)s_slot;

  extern __shared__ char sm[];
  const int wv = tid >> 6;           // wave id = batch tile (16 rows each)
  const int lane = tid & 63;

  // ---- stage genotype weights into LDS, fragment-major (swapped A-op) ----
  // layout: [gi(8)][half(2)][kc(8)][lane(64)][8 bf16]
  for (int c = 0; c < 32; ++c) {
    int flat = tid + 256 * c;
    int fl = flat & 63, kc = (flat >> 6) & 7, n = (flat >> 9) & 1, gi = flat >> 10;
    int col = n * 256 + wg * 16 + (fl & 15);
    int kb = kc * 32 + (fl >> 4) * 8;
    bf16x8 v;
#pragma unroll
    for (int e = 0; e < 8; ++e) v[e] = (short)f2bf(Wsg[(gi * 256 + kb + e) * 512 + col]);
    *(bf16x8*)(&sm[flat * 16]) = v;
  }

  // ---- W0 A-fragments (K=512 -> 16 k-chunks) into VGPRs ----
  bf16x8 w0c[16], w0h[16];
#pragma unroll
  for (int kc = 0; kc < 16; ++kc) {
    int kb = kc * 32 + (lane >> 4) * 8;
    bf16x8 vc, vh;
#pragma unroll
    for (int e = 0; e < 8; ++e) {
      vc[e] = (short)f2bf(W0g[(kb + e) * 512 + wg * 16 + (lane & 15)]);
      vh[e] = (short)f2bf(W0g[(kb + e) * 512 + 256 + wg * 16 + (lane & 15)]);
    }
    w0c[kc] = vc; w0h[kc] = vh;
  }

  // Ownership (swapped C-layout): batch row m, state cols n0..n0+3.
  const int m = wv * 16 + (lane & 15);
  const int n0 = wg * 16 + (lane >> 4) * 4;

  float hprev[4];
  float st[9][4];
  {
    f32x4 h4 = *(const f32x4*)(hid + m * 256 + n0);
#pragma unroll
    for (int r = 0; r < 4; ++r) hprev[r] = h4[r];
  }

  // Exchange-buffer write offset (shorts), constant per thread.
  const int wbase = ((((wg >> 1) * 4 + wv) * 64 +
                      (lane & 15) + 16 * ((wg * 2 + (lane >> 5)) & 3)) * 8) +
                    ((lane >> 4) & 1) * 4;

  __syncthreads();  // LDS weights ready

  unsigned short* sfh = sf + 6 * 16384;
  const unsigned* const pollMALL = flags + (lane & 15);       // MALL copy line
  const unsigned* const pollL2 = flags + 16 + (lane & 15);    // L2 copy line
  float* const outp = out + (size_t)m * 256 + n0;

  // Release: drain own stores (ack'd in the shared XCD L2), join wg, tid0
  // publishes the token to BOTH flag copies.
#define PUBLISH(TOK) do { \
    unsigned tk_ = (unsigned)(TOK); \
    asm volatile("s_waitcnt vmcnt(0)" ::: "memory"); \
    __syncthreads(); \
    if (tid == 0) { \
      asm volatile("global_store_dword %0, %1, off sc0" \
                   :: "v"(flags + 16 + wg), "v"(tk_) : "memory"); \
      asm volatile("global_store_dword %0, %1, off sc0 sc1" \
                   :: "v"(flags + wg), "v"(tk_) : "memory"); \
    } \
  } while (0)

  // Acquire: wave 0 spins on the L2 flag copy; after 16 misses it also
  // checks the MALL copy each iteration (graceful degrade, never hangs).
#define POLL(TOK) do { \
    unsigned tk_ = (unsigned)(TOK); \
    if (tk_) { \
      if (wv == 0) { \
        unsigned fv_; int it_ = 0; \
        for (;;) { \
          asm volatile("global_load_dword %0, %1, off sc0\n\t" \
                       "s_waitcnt vmcnt(0)" \
                       : "=v"(fv_) : "v"(pollL2) : "memory"); \
          if (!__any((int)(fv_ < tk_))) break; \
          if (++it_ >= 16) { \
            asm volatile("global_load_dword %0, %1, off sc0 sc1\n\t" \
                         "s_waitcnt vmcnt(0)" \
                         : "=v"(fv_) : "v"(pollMALL) : "memory"); \
            if (!__any((int)(fv_ < tk_))) break; \
          } \
        } \
      } \
      __syncthreads(); \
    } \
  } while (0)

#define GBAR(TOK) do { PUBLISH(TOK); POLL(TOK); } while (0)

#define LOADA(BUF) do { _Pragma("unroll") \
    for (int kc = 0; kc < 8; ++kc) \
      lda_sc(a[kc], (const unsigned short*)(BUF) + ((kc * 4 + wv) * 64 + lane) * 8); \
    ASM_WAIT8(a); \
  } while (0)

  // Swapped: A-operand = weight frag (LDS), B-operand = state frag.
#define MM(GI, AC, AH) do { _Pragma("unroll") \
    for (int kc = 0; kc < 8; ++kc) { \
      bf16x8 bc = *(const bf16x8*)(&sm[((((GI) * 2 + 0) * 8 + kc) * 64 + lane) * 16]); \
      bf16x8 bh = *(const bf16x8*)(&sm[((((GI) * 2 + 1) * 8 + kc) * 64 + lane) * 16]); \
      AC = __builtin_amdgcn_mfma_f32_16x16x32_bf16(bc, a[kc], AC, 0, 0, 0); \
      AH = __builtin_amdgcn_mfma_f32_16x16x32_bf16(bh, a[kc], AH, 0, 0, 0); \
    } } while (0)

#define UPD(SI, PR, ACT, AC, AH) do { _Pragma("unroll") \
    for (int r = 0; r < 4; ++r) { \
      float g = sigm((AC)[r]); float hh = (AH)[r]; \
      float av = (ACT) == 0 ? fmaxf(hh, 0.0f) : ((ACT) == 1 ? tanh_f(hh) : hh); \
      st[SI][r] = st[PR][r] + g * (av - st[PR][r]); \
    } } while (0)

  // One packed dwordx2 per thread: 4 consecutive bf16 at wbase (L2 scope).
#define STOREF(BUF, SI) do { \
    unsigned lo_ = (unsigned)f2bf(st[SI][0]) | ((unsigned)f2bf(st[SI][1]) << 16); \
    unsigned hi_ = (unsigned)f2bf(st[SI][2]) | ((unsigned)f2bf(st[SI][3]) << 16); \
    u32x2 v_; v_[0] = lo_; v_[1] = hi_; \
    asm volatile("global_store_dwordx2 %0, %1, off sc0" \
                 :: "v"((unsigned short*)(BUF) + wbase), "v"(v_) : "memory"); \
  } while (0)

#pragma clang loop unroll(disable)
  for (int t = 0; t < TT; ++t) {
    // ---- slot A, x-half (independent of h): overlaps the step-boundary wait
    f32x4 c0 = {0, 0, 0, 0}, h0 = {0, 0, 0, 0};
    {
      bf16x8 ax[8];
#pragma unroll
      for (int kc = 0; kc < 8; ++kc) {
        const float* px = x + ((t * 64 + m) * 256 + kc * 32 + (lane >> 4) * 8);
        bf16x8 v;
#pragma unroll
        for (int e = 0; e < 8; ++e) v[e] = (short)f2bf(px[e]);
        ax[kc] = v;
      }
#pragma unroll
      for (int kc = 0; kc < 8; ++kc) {
        c0 = __builtin_amdgcn_mfma_f32_16x16x32_bf16(w0c[kc], ax[kc], c0, 0, 0, 0);
        h0 = __builtin_amdgcn_mfma_f32_16x16x32_bf16(w0h[kc], ax[kc], h0, 0, 0, 0);
      }
    }
    POLL(t * 7);  // h-frags of step t ready (t=0: init data, no wait)
    // ---- slot A, h-half ----
    {
      bf16x8 ahf[8];
#pragma unroll
      for (int kc = 0; kc < 8; ++kc)
        lda_sc(ahf[kc], sfh + ((kc * 4 + wv) * 64 + lane) * 8);
      ASM_WAIT8(ahf);
#pragma unroll
      for (int kc = 0; kc < 8; ++kc) {
        c0 = __builtin_amdgcn_mfma_f32_16x16x32_bf16(w0c[8 + kc], ahf[kc], c0, 0, 0, 0);
        h0 = __builtin_amdgcn_mfma_f32_16x16x32_bf16(w0h[8 + kc], ahf[kc], h0, 0, 0, 0);
      }
#pragma unroll
      for (int r = 0; r < 4; ++r) {
        float g = sigm(c0[r]);
        float th = tanh_f(h0[r]);
        st[0][r] = hprev[r] + g * (th - hprev[r]);
      }
      STOREF(sf + 0 * 16384, 0);
    }
    GBAR(t * 7 + 1);

    bf16x8 a[8];
    // ---- slot B: s1 (geno0 relu, pred s0) ----
    {
      LOADA(sf + 0 * 16384);
      f32x4 ac = {0, 0, 0, 0}, ah = {0, 0, 0, 0};
      MM(0, ac, ah);
      UPD(1, 0, 0, ac, ah);
      STOREF(sf + 1 * 16384, 1);
    }
    GBAR(t * 7 + 2);
    // ---- slot C: s2 on the chain; s6/s8 local-only between pub and poll ----
    {
      LOADA(sf + 1 * 16384);
      f32x4 c2 = {0, 0, 0, 0}, h2 = {0, 0, 0, 0};
      MM(1, c2, h2);
      UPD(2, 1, 0, c2, h2);
      STOREF(sf + 2 * 16384, 2);
      PUBLISH(t * 7 + 3);
      f32x4 c6 = {0, 0, 0, 0}, h6 = {0, 0, 0, 0}, c8 = {0, 0, 0, 0}, h8 = {0, 0, 0, 0};
      MM(5, c6, h6); MM(7, c8, h8);   // a[] still holds s1 frags
      UPD(6, 1, 2, c6, h6);
      UPD(8, 1, 0, c8, h8);
      POLL(t * 7 + 3);
    }
    // ---- slot D: s3 (geno2 tanh, pred s2) ----
    {
      LOADA(sf + 2 * 16384);
      f32x4 ac = {0, 0, 0, 0}, ah = {0, 0, 0, 0};
      MM(2, ac, ah);
      UPD(3, 2, 1, ac, ah);
      STOREF(sf + 3 * 16384, 3);
    }
    GBAR(t * 7 + 4);
    // ---- slot E: s4 (geno3 relu, pred s3) ----
    {
      LOADA(sf + 3 * 16384);
      f32x4 ac = {0, 0, 0, 0}, ah = {0, 0, 0, 0};
      MM(3, ac, ah);
      UPD(4, 3, 0, ac, ah);
      STOREF(sf + 4 * 16384, 4);
    }
    GBAR(t * 7 + 5);
    // ---- slot F: s5 (geno4 relu, pred s4) ----
    {
      LOADA(sf + 4 * 16384);
      f32x4 ac = {0, 0, 0, 0}, ah = {0, 0, 0, 0};
      MM(4, ac, ah);
      UPD(5, 4, 0, ac, ah);
      STOREF(sf + 5 * 16384, 5);
    }
    GBAR(t * 7 + 6);
    // ---- slot G: s7 (geno6 relu, pred s5) local; h = mean(s1..s8) ----
    {
      LOADA(sf + 5 * 16384);
      f32x4 ac = {0, 0, 0, 0}, ah = {0, 0, 0, 0};
      MM(6, ac, ah);
      UPD(7, 5, 0, ac, ah);
      float hv[4];
#pragma unroll
      for (int r = 0; r < 4; ++r) {
        hv[r] = (st[1][r] + st[2][r] + st[3][r] + st[4][r] +
                 st[5][r] + st[6][r] + st[7][r] + st[8][r]) * 0.125f;
        hprev[r] = hv[r];
      }
      {
        unsigned lo_ = (unsigned)f2bf(hv[0]) | ((unsigned)f2bf(hv[1]) << 16);
        unsigned hi_ = (unsigned)f2bf(hv[2]) | ((unsigned)f2bf(hv[3]) << 16);
        u32x2 v_; v_[0] = lo_; v_[1] = hi_;
        asm volatile("global_store_dwordx2 %0, %1, off sc0"
                     :: "v"(sfh + wbase), "v"(v_) : "memory");
      }
      PUBLISH(t * 7 + 7);   // next iter's POLL((t+1)*7) pairs with this
      // out stores (nobody reads during the kernel) after the publish:
      f32x4 o4 = {hv[0], hv[1], hv[2], hv[3]};
      *(f32x4*)(outp + (size_t)t * 16384) = o4;
      if (t == TT - 1) *(f32x4*)(out + 16777216 + (size_t)m * 256 + n0) = o4;
    }
  }
#undef PUBLISH
#undef POLL
#undef GBAR
#undef LOADA
#undef MM
#undef UPD
#undef STOREF
}

extern "C" void kernel_launch(void* const* d_in, const int* in_sizes, int n_in,
                              void* d_out, int out_size, void* d_ws, size_t ws_size,
                              hipStream_t stream) {
  const float* x   = (const float*)d_in[0];   // [1024,64,256] f32
  const float* hid = (const float*)d_in[1];   // [1,64,256] f32
  const float* W0  = (const float*)d_in[2];   // [512,512] f32
  const float* Ws  = (const float*)d_in[3];   // [8,256,512] f32
  float* out = (float*)d_out;
  unsigned short* sf = (unsigned short*)d_ws;              // 7 x 16384 bf16 frag bufs
  unsigned* flags = (unsigned*)((char*)d_ws + 7 * 32768);  // flags + election state

  hipFuncSetAttribute((const void*)darts_main,
                      hipFuncAttributeMaxDynamicSharedMemorySize, 131072);
  darts_init<<<8, 256, 0, stream>>>(hid, sf, flags);
  darts_main<<<256, 256, 131072, stream>>>(x, hid, W0, Ws, out, sf, flags);
}

// Round 15
// 20377.643 us; speedup vs baseline: 1.5018x; 1.5018x over previous
//
#include <hip/hip_runtime.h>

// DARTS RNN cell, T=1024, B=64, NHID=NINP=256.
// 16 wgs x 256 threads (grid=16), wg n owns state cols [16n,16n+16).
// r13 PROVEN structure (20.2ms, best): sc0+sc1 (MALL) exchange; wg-joint
// flags (per-wave vmcnt(0) drain + __syncthreads + tid0 flag store, 16
// flags in ONE 64B line); SINGLE-POLLER (wave 0 polls, waves 1-3 released
// by barrier). Round 15 adds ONE thing: wave0's poll is 2-DEEP STAGGERED
// (persistent pf regs + POLL_FENCE lifetime containment, r10/r11/r12-proven
// machinery): flag line sampled every ~RT/2 instead of every RT, at only 32
// outstanding polls device-wide (r12's neutral result was at 128).
// r14 lesson (archived): sc0-only exchange keeps data in the XCD L2
// (FETCH 1.19GB -> 38MB) but sc0 flag loads can be served from the local
// L1 -> flags never observed -> only the MALL fallback synced. One-XCD
// is a dead end without a reliable intra-XCD flag primitive.
// Operand-swapped MFMAs (W as A-op); exchange write = ONE dwordx2;
// s6/s7/s8 local-only (slot-C window). Ws in LDS (128KB); W0 in VGPRs.

#define TT 1024
#define NWG 16

typedef __attribute__((ext_vector_type(8))) short bf16x8;
typedef __attribute__((ext_vector_type(4))) float f32x4;
typedef __attribute__((ext_vector_type(2))) unsigned int u32x2;

__device__ __forceinline__ unsigned short f2bf(float f) {
  unsigned u = __builtin_bit_cast(unsigned, f);
  u += 0x7FFFu + ((u >> 16) & 1u);   // round-to-nearest-even
  return (unsigned short)(u >> 16);
}
__device__ __forceinline__ float sigm(float c) { return 1.0f / (1.0f + __expf(-c)); }
__device__ __forceinline__ float tanh_f(float h) {
  float e = __expf(2.0f * h);        // inf-safe
  return 1.0f - 2.0f / (e + 1.0f);
}

// Device-coherent (MALL) 16B load; pair with ASM_WAIT8 before use.
__device__ __forceinline__ void lda_sc(bf16x8& r, const void* p) {
  asm volatile("global_load_dwordx4 %0, %1, off sc0 sc1" : "=v"(r) : "v"(p));
}
#define ASM_WAIT8(A) asm volatile("s_waitcnt vmcnt(0)" \
  : "+v"((A)[0]), "+v"((A)[1]), "+v"((A)[2]), "+v"((A)[3]), \
    "+v"((A)[4]), "+v"((A)[5]), "+v"((A)[6]), "+v"((A)[7]) :: "memory")

// Init: zero flags; convert initial hidden -> bf16 B-fragment buffer.
__global__ void darts_init(const float* __restrict__ hid,
                           unsigned short* __restrict__ sf,
                           unsigned* __restrict__ flags) {
  int tid = blockIdx.x * 256 + threadIdx.x;  // 2048 threads
  if (tid < 512) flags[tid] = 0;
  int lane = tid & 63, mt = (tid >> 6) & 3, kc = tid >> 8;
  const float* ph = hid + (mt * 16 + (lane & 15)) * 256 + kc * 32 + (lane >> 4) * 8;
  bf16x8 v;
#pragma unroll
  for (int e = 0; e < 8; ++e) v[e] = (short)f2bf(ph[e]);
  *(bf16x8*)(sf + 6 * 16384 + tid * 8) = v;  // tid == ((kc*4+mt)*64+lane)
}

__global__ void __launch_bounds__(256, 1) darts_main(
    const float* __restrict__ x, const float* __restrict__ hid,
    const float* __restrict__ W0g, const float* __restrict__ Wsg,
    float* __restrict__ out,
    unsigned short* __restrict__ sf, unsigned* __restrict__ flags) {
  extern __shared__ char sm[];
  const int wg = blockIdx.x, tid = threadIdx.x;
  const int wv = tid >> 6;           // wave id = batch tile (16 rows each)
  const int lane = tid & 63;

  // ---- stage genotype weights into LDS, fragment-major (swapped A-op) ----
  // layout: [gi(8)][half(2)][kc(8)][lane(64)][8 bf16]
  for (int c = 0; c < 32; ++c) {
    int flat = tid + 256 * c;
    int fl = flat & 63, kc = (flat >> 6) & 7, n = (flat >> 9) & 1, gi = flat >> 10;
    int col = n * 256 + wg * 16 + (fl & 15);
    int kb = kc * 32 + (fl >> 4) * 8;
    bf16x8 v;
#pragma unroll
    for (int e = 0; e < 8; ++e) v[e] = (short)f2bf(Wsg[(gi * 256 + kb + e) * 512 + col]);
    *(bf16x8*)(&sm[flat * 16]) = v;
  }

  // ---- W0 A-fragments (K=512 -> 16 k-chunks) into VGPRs ----
  bf16x8 w0c[16], w0h[16];
#pragma unroll
  for (int kc = 0; kc < 16; ++kc) {
    int kb = kc * 32 + (lane >> 4) * 8;
    bf16x8 vc, vh;
#pragma unroll
    for (int e = 0; e < 8; ++e) {
      vc[e] = (short)f2bf(W0g[(kb + e) * 512 + wg * 16 + (lane & 15)]);
      vh[e] = (short)f2bf(W0g[(kb + e) * 512 + 256 + wg * 16 + (lane & 15)]);
    }
    w0c[kc] = vc; w0h[kc] = vh;
  }

  // Ownership (swapped C-layout): batch row m, state cols n0..n0+3.
  const int m = wv * 16 + (lane & 15);
  const int n0 = wg * 16 + (lane >> 4) * 4;

  float hprev[4];
  float st[9][4];
  {
    f32x4 h4 = *(const f32x4*)(hid + m * 256 + n0);
#pragma unroll
    for (int r = 0; r < 4; ++r) hprev[r] = h4[r];
  }

  // Exchange-buffer write offset (shorts), constant per thread.
  const int wbase = ((((wg >> 1) * 4 + wv) * 64 +
                      (lane & 15) + 16 * ((wg * 2 + (lane >> 5)) & 3)) * 8) +
                    ((lane >> 4) & 1) * 4;

  __syncthreads();  // LDS weights ready

  unsigned short* sfh = sf + 6 * 16384;
  const unsigned* const pollp = flags + (lane & 15);   // the ONE hot 64B line
  float* const outp = out + (size_t)m * 256 + n0;

  // Persistent 2-deep staggered-poll registers (only wave 0 uses them);
  // POLL_FENCE after each vmcnt(0) drain extends their liveness so async
  // writebacks of in-flight poll loads always land in reserved registers.
  unsigned pf0 = 0, pf1 = 0;
#define POLL_FENCE() asm volatile("" : "+v"(pf0), "+v"(pf1))

  // Release: drain own stores to MALL, join wg, tid0 publishes wg flag.
#define PUBLISH(TOK) do { \
    unsigned tk_ = (unsigned)(TOK); \
    asm volatile("s_waitcnt vmcnt(0)" ::: "memory"); \
    POLL_FENCE(); \
    __syncthreads(); \
    if (tid == 0) \
      asm volatile("global_store_dword %0, %1, off sc0 sc1" \
                   :: "v"(flags + wg), "v"(tk_) : "memory"); \
  } while (0)

  // Acquire: wave 0 polls the flag line 2-deep staggered (sample ~RT/2);
  // may exit with one load in flight (drained at the next vmcnt(0) +
  // POLL_FENCE). Waves 1-3 wait at the barrier and are released on detect.
#define POLL(TOK) do { \
    unsigned tk_ = (unsigned)(TOK); \
    if (tk_) { \
      if (wv == 0) { \
        asm volatile( \
          "global_load_dword %0, %2, off sc0 sc1\n\t" \
          "global_load_dword %1, %2, off sc0 sc1" \
          : "=&v"(pf0), "=&v"(pf1) : "v"(pollp)); \
        for (;;) { \
          asm volatile("s_waitcnt vmcnt(1)" : "+v"(pf0) :: "memory"); \
          if (!__any((int)(pf0 < tk_))) break; \
          asm volatile("global_load_dword %0, %1, off sc0 sc1" \
                       : "=&v"(pf0) : "v"(pollp)); \
          asm volatile("s_waitcnt vmcnt(1)" : "+v"(pf1) :: "memory"); \
          if (!__any((int)(pf1 < tk_))) break; \
          asm volatile("global_load_dword %0, %1, off sc0 sc1" \
                       : "=&v"(pf1) : "v"(pollp)); \
        } \
      } \
      __syncthreads(); \
    } \
  } while (0)

#define GBAR(TOK) do { PUBLISH(TOK); POLL(TOK); } while (0)

#define LOADA(BUF) do { _Pragma("unroll") \
    for (int kc = 0; kc < 8; ++kc) \
      lda_sc(a[kc], (const unsigned short*)(BUF) + ((kc * 4 + wv) * 64 + lane) * 8); \
    ASM_WAIT8(a); \
    POLL_FENCE(); \
  } while (0)

  // Swapped: A-operand = weight frag (LDS), B-operand = state frag.
#define MM(GI, AC, AH) do { _Pragma("unroll") \
    for (int kc = 0; kc < 8; ++kc) { \
      bf16x8 bc = *(const bf16x8*)(&sm[((((GI) * 2 + 0) * 8 + kc) * 64 + lane) * 16]); \
      bf16x8 bh = *(const bf16x8*)(&sm[((((GI) * 2 + 1) * 8 + kc) * 64 + lane) * 16]); \
      AC = __builtin_amdgcn_mfma_f32_16x16x32_bf16(bc, a[kc], AC, 0, 0, 0); \
      AH = __builtin_amdgcn_mfma_f32_16x16x32_bf16(bh, a[kc], AH, 0, 0, 0); \
    } } while (0)

#define UPD(SI, PR, ACT, AC, AH) do { _Pragma("unroll") \
    for (int r = 0; r < 4; ++r) { \
      float g = sigm((AC)[r]); float hh = (AH)[r]; \
      float av = (ACT) == 0 ? fmaxf(hh, 0.0f) : ((ACT) == 1 ? tanh_f(hh) : hh); \
      st[SI][r] = st[PR][r] + g * (av - st[PR][r]); \
    } } while (0)

  // One packed dwordx2 per thread: 4 consecutive bf16 at wbase.
#define STOREF(BUF, SI) do { \
    unsigned lo_ = (unsigned)f2bf(st[SI][0]) | ((unsigned)f2bf(st[SI][1]) << 16); \
    unsigned hi_ = (unsigned)f2bf(st[SI][2]) | ((unsigned)f2bf(st[SI][3]) << 16); \
    u32x2 v_; v_[0] = lo_; v_[1] = hi_; \
    asm volatile("global_store_dwordx2 %0, %1, off sc0 sc1" \
                 :: "v"((unsigned short*)(BUF) + wbase), "v"(v_) : "memory"); \
  } while (0)

#pragma clang loop unroll(disable)
  for (int t = 0; t < TT; ++t) {
    // ---- slot A, x-half (independent of h): overlaps the step-boundary wait
    f32x4 c0 = {0, 0, 0, 0}, h0 = {0, 0, 0, 0};
    {
      bf16x8 ax[8];
#pragma unroll
      for (int kc = 0; kc < 8; ++kc) {
        const float* px = x + ((t * 64 + m) * 256 + kc * 32 + (lane >> 4) * 8);
        bf16x8 v;
#pragma unroll
        for (int e = 0; e < 8; ++e) v[e] = (short)f2bf(px[e]);
        ax[kc] = v;
      }
#pragma unroll
      for (int kc = 0; kc < 8; ++kc) {
        c0 = __builtin_amdgcn_mfma_f32_16x16x32_bf16(w0c[kc], ax[kc], c0, 0, 0, 0);
        h0 = __builtin_amdgcn_mfma_f32_16x16x32_bf16(w0h[kc], ax[kc], h0, 0, 0, 0);
      }
    }
    POLL(t * 7);  // h-frags of step t ready (t=0: init data, no wait)
    // ---- slot A, h-half ----
    {
      bf16x8 ahf[8];
#pragma unroll
      for (int kc = 0; kc < 8; ++kc)
        lda_sc(ahf[kc], sfh + ((kc * 4 + wv) * 64 + lane) * 8);
      ASM_WAIT8(ahf);
      POLL_FENCE();
#pragma unroll
      for (int kc = 0; kc < 8; ++kc) {
        c0 = __builtin_amdgcn_mfma_f32_16x16x32_bf16(w0c[8 + kc], ahf[kc], c0, 0, 0, 0);
        h0 = __builtin_amdgcn_mfma_f32_16x16x32_bf16(w0h[8 + kc], ahf[kc], h0, 0, 0, 0);
      }
#pragma unroll
      for (int r = 0; r < 4; ++r) {
        float g = sigm(c0[r]);
        float th = tanh_f(h0[r]);
        st[0][r] = hprev[r] + g * (th - hprev[r]);
      }
      STOREF(sf + 0 * 16384, 0);
    }
    GBAR(t * 7 + 1);

    bf16x8 a[8];
    // ---- slot B: s1 (geno0 relu, pred s0) ----
    {
      LOADA(sf + 0 * 16384);
      f32x4 ac = {0, 0, 0, 0}, ah = {0, 0, 0, 0};
      MM(0, ac, ah);
      UPD(1, 0, 0, ac, ah);
      STOREF(sf + 1 * 16384, 1);
    }
    GBAR(t * 7 + 2);
    // ---- slot C: s2 on the chain; s6/s8 local-only between pub and poll ----
    {
      LOADA(sf + 1 * 16384);
      f32x4 c2 = {0, 0, 0, 0}, h2 = {0, 0, 0, 0};
      MM(1, c2, h2);
      UPD(2, 1, 0, c2, h2);
      STOREF(sf + 2 * 16384, 2);
      PUBLISH(t * 7 + 3);
      f32x4 c6 = {0, 0, 0, 0}, h6 = {0, 0, 0, 0}, c8 = {0, 0, 0, 0}, h8 = {0, 0, 0, 0};
      MM(5, c6, h6); MM(7, c8, h8);   // a[] still holds s1 frags
      UPD(6, 1, 2, c6, h6);
      UPD(8, 1, 0, c8, h8);
      POLL(t * 7 + 3);
    }
    // ---- slot D: s3 (geno2 tanh, pred s2) ----
    {
      LOADA(sf + 2 * 16384);
      f32x4 ac = {0, 0, 0, 0}, ah = {0, 0, 0, 0};
      MM(2, ac, ah);
      UPD(3, 2, 1, ac, ah);
      STOREF(sf + 3 * 16384, 3);
    }
    GBAR(t * 7 + 4);
    // ---- slot E: s4 (geno3 relu, pred s3) ----
    {
      LOADA(sf + 3 * 16384);
      f32x4 ac = {0, 0, 0, 0}, ah = {0, 0, 0, 0};
      MM(3, ac, ah);
      UPD(4, 3, 0, ac, ah);
      STOREF(sf + 4 * 16384, 4);
    }
    GBAR(t * 7 + 5);
    // ---- slot F: s5 (geno4 relu, pred s4) ----
    {
      LOADA(sf + 4 * 16384);
      f32x4 ac = {0, 0, 0, 0}, ah = {0, 0, 0, 0};
      MM(4, ac, ah);
      UPD(5, 4, 0, ac, ah);
      STOREF(sf + 5 * 16384, 5);
    }
    GBAR(t * 7 + 6);
    // ---- slot G: s7 (geno6 relu, pred s5) local; h = mean(s1..s8) ----
    {
      LOADA(sf + 5 * 16384);
      f32x4 ac = {0, 0, 0, 0}, ah = {0, 0, 0, 0};
      MM(6, ac, ah);
      UPD(7, 5, 0, ac, ah);
      float hv[4];
#pragma unroll
      for (int r = 0; r < 4; ++r) {
        hv[r] = (st[1][r] + st[2][r] + st[3][r] + st[4][r] +
                 st[5][r] + st[6][r] + st[7][r] + st[8][r]) * 0.125f;
        hprev[r] = hv[r];
      }
      {
        unsigned lo_ = (unsigned)f2bf(hv[0]) | ((unsigned)f2bf(hv[1]) << 16);
        unsigned hi_ = (unsigned)f2bf(hv[2]) | ((unsigned)f2bf(hv[3]) << 16);
        u32x2 v_; v_[0] = lo_; v_[1] = hi_;
        asm volatile("global_store_dwordx2 %0, %1, off sc0 sc1"
                     :: "v"(sfh + wbase), "v"(v_) : "memory");
      }
      PUBLISH(t * 7 + 7);   // next iter's POLL((t+1)*7) pairs with this
      // out stores (nobody reads during the kernel) after the publish:
      f32x4 o4 = {hv[0], hv[1], hv[2], hv[3]};
      *(f32x4*)(outp + (size_t)t * 16384) = o4;
      if (t == TT - 1) *(f32x4*)(out + 16777216 + (size_t)m * 256 + n0) = o4;
    }
  }
#undef POLL_FENCE
#undef PUBLISH
#undef POLL
#undef GBAR
#undef LOADA
#undef MM
#undef UPD
#undef STOREF
}

extern "C" void kernel_launch(void* const* d_in, const int* in_sizes, int n_in,
                              void* d_out, int out_size, void* d_ws, size_t ws_size,
                              hipStream_t stream) {
  const float* x   = (const float*)d_in[0];   // [1024,64,256] f32
  const float* hid = (const float*)d_in[1];   // [1,64,256] f32
  const float* W0  = (const float*)d_in[2];   // [512,512] f32
  const float* Ws  = (const float*)d_in[3];   // [8,256,512] f32
  float* out = (float*)d_out;
  unsigned short* sf = (unsigned short*)d_ws;              // 7 x 16384 bf16 frag bufs
  unsigned* flags = (unsigned*)((char*)d_ws + 7 * 32768);  // 16 wg flags, ONE 64B line

  hipFuncSetAttribute((const void*)darts_main,
                      hipFuncAttributeMaxDynamicSharedMemorySize, 131072);
  darts_init<<<8, 256, 0, stream>>>(hid, sf, flags);
  darts_main<<<NWG, 256, 131072, stream>>>(x, hid, W0, Ws, out, sf, flags);
}

// Round 16
// 19517.052 us; speedup vs baseline: 1.5681x; 1.0441x over previous
//
#include <hip/hip_runtime.h>

// DARTS RNN cell, T=1024, B=64, NHID=NINP=256.
// FINAL CONFIGURATION = round-13 kernel, byte-identical (best: 20.2ms).
// 16 wgs x 256 threads (grid=16), wg n owns state cols [16n,16n+16).
// Protocol: sc0+sc1 (MALL, device-coherent) exchange; wg-joint flags
// (per-wave vmcnt(0) drain + __syncthreads + tid0 flag store; 16 flags in
// ONE 64B line); SINGLE-POLLER (wave 0 polls, waves 1-3 barrier-released).
// Operand-swapped MFMAs (W as A-op, lane owns 1 batch row x 4 state cols);
// exchange write = ONE dwordx2/thread; s6/s7/s8 local-only in slot-C's
// publish window; slot-A x-half hoisted above the step-boundary poll;
// Ws stationary in LDS (128KB fragment-major); W0 in VGPRs.
// Plateau evidence: polling space swept ({64,16} pollers x {1,2,4}-deep,
// rings, L2-local flags, token packets) -> all within noise or worse.
// Slot cost 2.8us = drain RT + flag propagate + max-of-16 detect + reload
// RT + skew; 7168 such syncs on the critical path.

#define TT 1024
#define NWG 16

typedef __attribute__((ext_vector_type(8))) short bf16x8;
typedef __attribute__((ext_vector_type(4))) float f32x4;
typedef __attribute__((ext_vector_type(2))) unsigned int u32x2;

__device__ __forceinline__ unsigned short f2bf(float f) {
  unsigned u = __builtin_bit_cast(unsigned, f);
  u += 0x7FFFu + ((u >> 16) & 1u);   // round-to-nearest-even
  return (unsigned short)(u >> 16);
}
__device__ __forceinline__ float sigm(float c) { return 1.0f / (1.0f + __expf(-c)); }
__device__ __forceinline__ float tanh_f(float h) {
  float e = __expf(2.0f * h);        // inf-safe
  return 1.0f - 2.0f / (e + 1.0f);
}

// Device-coherent (MALL) 16B load; pair with ASM_WAIT8 before use.
__device__ __forceinline__ void lda_sc(bf16x8& r, const void* p) {
  asm volatile("global_load_dwordx4 %0, %1, off sc0 sc1" : "=v"(r) : "v"(p));
}
#define ASM_WAIT8(A) asm volatile("s_waitcnt vmcnt(0)" \
  : "+v"((A)[0]), "+v"((A)[1]), "+v"((A)[2]), "+v"((A)[3]), \
    "+v"((A)[4]), "+v"((A)[5]), "+v"((A)[6]), "+v"((A)[7]) :: "memory")

// Init: zero flags; convert initial hidden -> bf16 B-fragment buffer.
__global__ void darts_init(const float* __restrict__ hid,
                           unsigned short* __restrict__ sf,
                           unsigned* __restrict__ flags) {
  int tid = blockIdx.x * 256 + threadIdx.x;  // 2048 threads
  if (tid < 512) flags[tid] = 0;
  int lane = tid & 63, mt = (tid >> 6) & 3, kc = tid >> 8;
  const float* ph = hid + (mt * 16 + (lane & 15)) * 256 + kc * 32 + (lane >> 4) * 8;
  bf16x8 v;
#pragma unroll
  for (int e = 0; e < 8; ++e) v[e] = (short)f2bf(ph[e]);
  *(bf16x8*)(sf + 6 * 16384 + tid * 8) = v;  // tid == ((kc*4+mt)*64+lane)
}

__global__ void __launch_bounds__(256, 1) darts_main(
    const float* __restrict__ x, const float* __restrict__ hid,
    const float* __restrict__ W0g, const float* __restrict__ Wsg,
    float* __restrict__ out,
    unsigned short* __restrict__ sf, unsigned* __restrict__ flags) {
  extern __shared__ char sm[];
  const int wg = blockIdx.x, tid = threadIdx.x;
  const int wv = tid >> 6;           // wave id = batch tile (16 rows each)
  const int lane = tid & 63;

  // ---- stage genotype weights into LDS, fragment-major (swapped A-op) ----
  // layout: [gi(8)][half(2)][kc(8)][lane(64)][8 bf16]
  for (int c = 0; c < 32; ++c) {
    int flat = tid + 256 * c;
    int fl = flat & 63, kc = (flat >> 6) & 7, n = (flat >> 9) & 1, gi = flat >> 10;
    int col = n * 256 + wg * 16 + (fl & 15);
    int kb = kc * 32 + (fl >> 4) * 8;
    bf16x8 v;
#pragma unroll
    for (int e = 0; e < 8; ++e) v[e] = (short)f2bf(Wsg[(gi * 256 + kb + e) * 512 + col]);
    *(bf16x8*)(&sm[flat * 16]) = v;
  }

  // ---- W0 A-fragments (K=512 -> 16 k-chunks) into VGPRs ----
  bf16x8 w0c[16], w0h[16];
#pragma unroll
  for (int kc = 0; kc < 16; ++kc) {
    int kb = kc * 32 + (lane >> 4) * 8;
    bf16x8 vc, vh;
#pragma unroll
    for (int e = 0; e < 8; ++e) {
      vc[e] = (short)f2bf(W0g[(kb + e) * 512 + wg * 16 + (lane & 15)]);
      vh[e] = (short)f2bf(W0g[(kb + e) * 512 + 256 + wg * 16 + (lane & 15)]);
    }
    w0c[kc] = vc; w0h[kc] = vh;
  }

  // Ownership (swapped C-layout): batch row m, state cols n0..n0+3.
  const int m = wv * 16 + (lane & 15);
  const int n0 = wg * 16 + (lane >> 4) * 4;

  float hprev[4];
  float st[9][4];
  {
    f32x4 h4 = *(const f32x4*)(hid + m * 256 + n0);
#pragma unroll
    for (int r = 0; r < 4; ++r) hprev[r] = h4[r];
  }

  // Exchange-buffer write offset (shorts), constant per thread.
  const int wbase = ((((wg >> 1) * 4 + wv) * 64 +
                      (lane & 15) + 16 * ((wg * 2 + (lane >> 5)) & 3)) * 8) +
                    ((lane >> 4) & 1) * 4;

  __syncthreads();  // LDS weights ready

  unsigned short* sfh = sf + 6 * 16384;
  const unsigned* const pollp = flags + (lane & 15);   // the ONE hot 64B line
  float* const outp = out + (size_t)m * 256 + n0;

  // Release: drain own stores to MALL, join wg, tid0 publishes wg flag.
#define PUBLISH(TOK) do { \
    unsigned tk_ = (unsigned)(TOK); \
    asm volatile("s_waitcnt vmcnt(0)" ::: "memory"); \
    __syncthreads(); \
    if (tid == 0) \
      asm volatile("global_store_dword %0, %1, off sc0 sc1" \
                   :: "v"(flags + wg), "v"(tk_) : "memory"); \
  } while (0)

  // Acquire: ONLY wave 0 polls the flag line; waves 1-3 wait at the barrier
  // and are released on detect (16 pollers on the line instead of 64).
#define POLL(TOK) do { \
    unsigned tk_ = (unsigned)(TOK); \
    if (tk_) { \
      if (wv == 0) { \
        unsigned fv_; \
        do { \
          asm volatile("global_load_dword %0, %1, off sc0 sc1\n\t" \
                       "s_waitcnt vmcnt(0)" \
                       : "=v"(fv_) : "v"(pollp) : "memory"); \
        } while (__any((int)(fv_ < tk_))); \
      } \
      __syncthreads(); \
    } \
  } while (0)

#define GBAR(TOK) do { PUBLISH(TOK); POLL(TOK); } while (0)

#define LOADA(BUF) do { _Pragma("unroll") \
    for (int kc = 0; kc < 8; ++kc) \
      lda_sc(a[kc], (const unsigned short*)(BUF) + ((kc * 4 + wv) * 64 + lane) * 8); \
    ASM_WAIT8(a); \
  } while (0)

  // Swapped: A-operand = weight frag (LDS), B-operand = state frag.
#define MM(GI, AC, AH) do { _Pragma("unroll") \
    for (int kc = 0; kc < 8; ++kc) { \
      bf16x8 bc = *(const bf16x8*)(&sm[((((GI) * 2 + 0) * 8 + kc) * 64 + lane) * 16]); \
      bf16x8 bh = *(const bf16x8*)(&sm[((((GI) * 2 + 1) * 8 + kc) * 64 + lane) * 16]); \
      AC = __builtin_amdgcn_mfma_f32_16x16x32_bf16(bc, a[kc], AC, 0, 0, 0); \
      AH = __builtin_amdgcn_mfma_f32_16x16x32_bf16(bh, a[kc], AH, 0, 0, 0); \
    } } while (0)

#define UPD(SI, PR, ACT, AC, AH) do { _Pragma("unroll") \
    for (int r = 0; r < 4; ++r) { \
      float g = sigm((AC)[r]); float hh = (AH)[r]; \
      float av = (ACT) == 0 ? fmaxf(hh, 0.0f) : ((ACT) == 1 ? tanh_f(hh) : hh); \
      st[SI][r] = st[PR][r] + g * (av - st[PR][r]); \
    } } while (0)

  // One packed dwordx2 per thread: 4 consecutive bf16 at wbase.
#define STOREF(BUF, SI) do { \
    unsigned lo_ = (unsigned)f2bf(st[SI][0]) | ((unsigned)f2bf(st[SI][1]) << 16); \
    unsigned hi_ = (unsigned)f2bf(st[SI][2]) | ((unsigned)f2bf(st[SI][3]) << 16); \
    u32x2 v_; v_[0] = lo_; v_[1] = hi_; \
    asm volatile("global_store_dwordx2 %0, %1, off sc0 sc1" \
                 :: "v"((unsigned short*)(BUF) + wbase), "v"(v_) : "memory"); \
  } while (0)

#pragma clang loop unroll(disable)
  for (int t = 0; t < TT; ++t) {
    // ---- slot A, x-half (independent of h): overlaps the step-boundary wait
    f32x4 c0 = {0, 0, 0, 0}, h0 = {0, 0, 0, 0};
    {
      bf16x8 ax[8];
#pragma unroll
      for (int kc = 0; kc < 8; ++kc) {
        const float* px = x + ((t * 64 + m) * 256 + kc * 32 + (lane >> 4) * 8);
        bf16x8 v;
#pragma unroll
        for (int e = 0; e < 8; ++e) v[e] = (short)f2bf(px[e]);
        ax[kc] = v;
      }
#pragma unroll
      for (int kc = 0; kc < 8; ++kc) {
        c0 = __builtin_amdgcn_mfma_f32_16x16x32_bf16(w0c[kc], ax[kc], c0, 0, 0, 0);
        h0 = __builtin_amdgcn_mfma_f32_16x16x32_bf16(w0h[kc], ax[kc], h0, 0, 0, 0);
      }
    }
    POLL(t * 7);  // h-frags of step t ready (t=0: init data, no wait)
    // ---- slot A, h-half ----
    {
      bf16x8 ahf[8];
#pragma unroll
      for (int kc = 0; kc < 8; ++kc)
        lda_sc(ahf[kc], sfh + ((kc * 4 + wv) * 64 + lane) * 8);
      ASM_WAIT8(ahf);
#pragma unroll
      for (int kc = 0; kc < 8; ++kc) {
        c0 = __builtin_amdgcn_mfma_f32_16x16x32_bf16(w0c[8 + kc], ahf[kc], c0, 0, 0, 0);
        h0 = __builtin_amdgcn_mfma_f32_16x16x32_bf16(w0h[8 + kc], ahf[kc], h0, 0, 0, 0);
      }
#pragma unroll
      for (int r = 0; r < 4; ++r) {
        float g = sigm(c0[r]);
        float th = tanh_f(h0[r]);
        st[0][r] = hprev[r] + g * (th - hprev[r]);
      }
      STOREF(sf + 0 * 16384, 0);
    }
    GBAR(t * 7 + 1);

    bf16x8 a[8];
    // ---- slot B: s1 (geno0 relu, pred s0) ----
    {
      LOADA(sf + 0 * 16384);
      f32x4 ac = {0, 0, 0, 0}, ah = {0, 0, 0, 0};
      MM(0, ac, ah);
      UPD(1, 0, 0, ac, ah);
      STOREF(sf + 1 * 16384, 1);
    }
    GBAR(t * 7 + 2);
    // ---- slot C: s2 on the chain; s6/s8 local-only between pub and poll ----
    {
      LOADA(sf + 1 * 16384);
      f32x4 c2 = {0, 0, 0, 0}, h2 = {0, 0, 0, 0};
      MM(1, c2, h2);
      UPD(2, 1, 0, c2, h2);
      STOREF(sf + 2 * 16384, 2);
      PUBLISH(t * 7 + 3);
      f32x4 c6 = {0, 0, 0, 0}, h6 = {0, 0, 0, 0}, c8 = {0, 0, 0, 0}, h8 = {0, 0, 0, 0};
      MM(5, c6, h6); MM(7, c8, h8);   // a[] still holds s1 frags
      UPD(6, 1, 2, c6, h6);
      UPD(8, 1, 0, c8, h8);
      POLL(t * 7 + 3);
    }
    // ---- slot D: s3 (geno2 tanh, pred s2) ----
    {
      LOADA(sf + 2 * 16384);
      f32x4 ac = {0, 0, 0, 0}, ah = {0, 0, 0, 0};
      MM(2, ac, ah);
      UPD(3, 2, 1, ac, ah);
      STOREF(sf + 3 * 16384, 3);
    }
    GBAR(t * 7 + 4);
    // ---- slot E: s4 (geno3 relu, pred s3) ----
    {
      LOADA(sf + 3 * 16384);
      f32x4 ac = {0, 0, 0, 0}, ah = {0, 0, 0, 0};
      MM(3, ac, ah);
      UPD(4, 3, 0, ac, ah);
      STOREF(sf + 4 * 16384, 4);
    }
    GBAR(t * 7 + 5);
    // ---- slot F: s5 (geno4 relu, pred s4) ----
    {
      LOADA(sf + 4 * 16384);
      f32x4 ac = {0, 0, 0, 0}, ah = {0, 0, 0, 0};
      MM(4, ac, ah);
      UPD(5, 4, 0, ac, ah);
      STOREF(sf + 5 * 16384, 5);
    }
    GBAR(t * 7 + 6);
    // ---- slot G: s7 (geno6 relu, pred s5) local; h = mean(s1..s8) ----
    {
      LOADA(sf + 5 * 16384);
      f32x4 ac = {0, 0, 0, 0}, ah = {0, 0, 0, 0};
      MM(6, ac, ah);
      UPD(7, 5, 0, ac, ah);
      float hv[4];
#pragma unroll
      for (int r = 0; r < 4; ++r) {
        hv[r] = (st[1][r] + st[2][r] + st[3][r] + st[4][r] +
                 st[5][r] + st[6][r] + st[7][r] + st[8][r]) * 0.125f;
        hprev[r] = hv[r];
      }
      {
        unsigned lo_ = (unsigned)f2bf(hv[0]) | ((unsigned)f2bf(hv[1]) << 16);
        unsigned hi_ = (unsigned)f2bf(hv[2]) | ((unsigned)f2bf(hv[3]) << 16);
        u32x2 v_; v_[0] = lo_; v_[1] = hi_;
        asm volatile("global_store_dwordx2 %0, %1, off sc0 sc1"
                     :: "v"(sfh + wbase), "v"(v_) : "memory");
      }
      PUBLISH(t * 7 + 7);   // next iter's POLL((t+1)*7) pairs with this
      // out stores (nobody reads during the kernel) after the publish:
      f32x4 o4 = {hv[0], hv[1], hv[2], hv[3]};
      *(f32x4*)(outp + (size_t)t * 16384) = o4;
      if (t == TT - 1) *(f32x4*)(out + 16777216 + (size_t)m * 256 + n0) = o4;
    }
  }
#undef PUBLISH
#undef POLL
#undef GBAR
#undef LOADA
#undef MM
#undef UPD
#undef STOREF
}

extern "C" void kernel_launch(void* const* d_in, const int* in_sizes, int n_in,
                              void* d_out, int out_size, void* d_ws, size_t ws_size,
                              hipStream_t stream) {
  const float* x   = (const float*)d_in[0];   // [1024,64,256] f32
  const float* hid = (const float*)d_in[1];   // [1,64,256] f32
  const float* W0  = (const float*)d_in[2];   // [512,512] f32
  const float* Ws  = (const float*)d_in[3];   // [8,256,512] f32
  float* out = (float*)d_out;
  unsigned short* sf = (unsigned short*)d_ws;              // 7 x 16384 bf16 frag bufs
  unsigned* flags = (unsigned*)((char*)d_ws + 7 * 32768);  // 16 wg flags, ONE 64B line

  hipFuncSetAttribute((const void*)darts_main,
                      hipFuncAttributeMaxDynamicSharedMemorySize, 131072);
  darts_init<<<8, 256, 0, stream>>>(hid, sf, flags);
  darts_main<<<NWG, 256, 131072, stream>>>(x, hid, W0, Ws, out, sf, flags);
}